// Round 15
// baseline (390.036 us; speedup 1.0000x reference)
//
#include <hip/hip_runtime.h>
#include <hip/hip_bf16.h>
#include <math.h>

#define BSZ 2
#define LSEQ 4096
#define DMODEL 1024
#define DINNER 2048
#define NSTATE 16
#define DTRANK 64
#define MROWS (BSZ * LSEQ)   // 8192
#define NCHUNK 64
#define CHUNK (LSEQ / NCHUNK)  // 64
#define XKS 8
#define XKCH (DINNER / XKS)    // 256

#if __has_builtin(__builtin_amdgcn_exp2f)
#define EXP2F(x) __builtin_amdgcn_exp2f(x)
#else
#define EXP2F(x) exp2f(x)
#endif
#define LOG2E 1.44269504088896f

typedef __attribute__((ext_vector_type(8))) short bf16x8;
typedef __attribute__((ext_vector_type(4))) float f32x4;

__device__ __forceinline__ float sigmoidf_(float x) { return 1.0f / (1.0f + __expf(-x)); }

__device__ __forceinline__ unsigned short f2bf(float x) {
    unsigned int u = __float_as_uint(x);
    u += 0x7fff + ((u >> 16) & 1);          // round-to-nearest-even
    return (unsigned short)(u >> 16);
}
__device__ __forceinline__ float bf2f(unsigned short b) {
    return __uint_as_float(((unsigned int)b) << 16);
}

// ---------------------------------------------------------------------------
// Fused operand prep (cvt x + 4 weight transposes), demuxed on blockIdx.
// Swizzle: element k of a 64-window stored at k ^ ((row&7)<<3).
// ---------------------------------------------------------------------------
__global__ __launch_bounds__(256) void prep_kernel(
    const float* __restrict__ x, unsigned short* __restrict__ xbf,
    const float* __restrict__ w_in, unsigned short* __restrict__ wT_in,
    const float* __restrict__ w_out, unsigned short* __restrict__ wT_out,
    const float* __restrict__ w_x, unsigned short* __restrict__ wXT,
    const float* __restrict__ w_dt, unsigned short* __restrict__ wDT)
{
    __shared__ float tile[64][65];
    const int id = blockIdx.x;
    const int t = threadIdx.x;

    if (id >= 1632) {   // cvt x -> xbf (K=1024, 128 groups of 8 per row)
        int gid = (id - 1632) * 256 + t;
        int m = gid >> 7;
        int g = gid & 127;
        size_t src = (size_t)m * 1024 + g * 8;
        float4 v0 = *reinterpret_cast<const float4*>(x + src);
        float4 v1 = *reinterpret_cast<const float4*>(x + src + 4);
        uint4 w;
        w.x = (unsigned)f2bf(v0.x) | ((unsigned)f2bf(v0.y) << 16);
        w.y = (unsigned)f2bf(v0.z) | ((unsigned)f2bf(v0.w) << 16);
        w.z = (unsigned)f2bf(v1.x) | ((unsigned)f2bf(v1.y) << 16);
        w.w = (unsigned)f2bf(v1.z) | ((unsigned)f2bf(v1.w) << 16);
        size_t dst = (size_t)m * 1024 + ((g * 8) ^ ((m & 7) << 3));
        *reinterpret_cast<uint4*>(xbf + dst) = w;
        return;
    }

    const float* W; unsigned short* WT; int K, Nsrc, nb, kb;
    if (id < 1024)      { W = w_in;  WT = wT_in;  K = 1024; Nsrc = 4096; nb = id & 63; kb = id >> 6; }
    else if (id < 1536) { int q = id - 1024; W = w_out; WT = wT_out; K = 2048; Nsrc = 1024; nb = q & 15; kb = q >> 4; }
    else if (id < 1600) { int q = id - 1536; W = w_x;   WT = wXT;   K = 2048; Nsrc = 96;   nb = q & 1;  kb = q >> 1; }
    else                { int q = id - 1600; W = w_dt;  WT = wDT;   K = 64;   Nsrc = 2048; nb = q;      kb = 0; }

    const int n0 = nb * 64;
    const int k0 = kb * 64;

    #pragma unroll
    for (int i = 0; i < 16; ++i) {
        int flat = i * 256 + t;
        int r = flat >> 6, c = flat & 63;
        tile[r][c] = (n0 + c < Nsrc) ? W[(size_t)(k0 + r) * Nsrc + n0 + c] : 0.0f;
    }
    __syncthreads();
    #pragma unroll
    for (int i = 0; i < 16; ++i) {
        int flat = i * 256 + t;
        int n = flat >> 6, k = flat & 63;
        int ks = k ^ ((n & 7) << 3);
        WT[(size_t)(n0 + n) * K + k0 + ks] = f2bf(tile[k][n]);
    }
}

// ---------------------------------------------------------------------------
// Pure-bf16 MFMA GEMM, 512 threads / 8 waves on a 128x128 tile; each wave
// owns 64x32 (acc = 4x2 f32x4 = 32 AGPR -> ~52% occupancy, r14-proven).
// OBF=1: bf16 C; OBF=0: fp32 C.
// ---------------------------------------------------------------------------
template<int OBF>
__global__ __launch_bounds__(512) void gemm_bb512_kernel(
    const unsigned short* __restrict__ Abf, const unsigned short* __restrict__ BT,
    void* __restrict__ Cv, int M, int N, int K, int ldc)
{
    __shared__ unsigned short lds_a[128 * 64];
    __shared__ unsigned short lds_b[128 * 64];

    const int tid  = threadIdx.x;
    const int lane = tid & 63;
    const int w    = tid >> 6;            // 0..7
    const int wr   = (w >> 2) * 64;       // 0 or 64
    const int wc   = (w & 3) * 32;        // 0,32,64,96
    const int row0 = blockIdx.y * 128;
    const int col0 = blockIdx.x * 128;

    f32x4 acc[4][2];
    #pragma unroll
    for (int m = 0; m < 4; ++m)
        #pragma unroll
        for (int n = 0; n < 2; ++n)
            acc[m][n] = (f32x4){0.f, 0.f, 0.f, 0.f};

    for (int k0 = 0; k0 < K; k0 += 64) {
        #pragma unroll
        for (int j = 0; j < 2; ++j) {
            int c  = j * 512 + tid;       // 16B chunk id, 0..1023
            int r  = c >> 3;
            int cc = c & 7;
            const char* asrc = (const char*)Abf +
                ((size_t)(row0 + r) * K + k0) * 2 + cc * 16;
            __builtin_amdgcn_global_load_lds(
                (const __attribute__((address_space(1))) void*)asrc,
                (__attribute__((address_space(3))) void*)((char*)lds_a + c * 16),
                16, 0, 0);
            const char* bsrc = (const char*)BT +
                ((size_t)(col0 + r) * K + k0) * 2 + cc * 16;
            __builtin_amdgcn_global_load_lds(
                (const __attribute__((address_space(1))) void*)bsrc,
                (__attribute__((address_space(3))) void*)((char*)lds_b + c * 16),
                16, 0, 0);
        }
        __syncthreads();

        #pragma unroll
        for (int kk = 0; kk < 2; ++kk) {
            bf16x8 af[4], bfr[2];
            #pragma unroll
            for (int m = 0; m < 4; ++m) {
                int r = wr + m * 16 + (lane & 15);
                int byteoff = r * 128 + ((kk * 64 + (lane >> 4) * 16) ^ ((r & 7) << 4));
                af[m] = *reinterpret_cast<const bf16x8*>((const char*)lds_a + byteoff);
            }
            #pragma unroll
            for (int n = 0; n < 2; ++n) {
                int r = wc + n * 16 + (lane & 15);
                int byteoff = r * 128 + ((kk * 64 + (lane >> 4) * 16) ^ ((r & 7) << 4));
                bfr[n] = *reinterpret_cast<const bf16x8*>((const char*)lds_b + byteoff);
            }
            #pragma unroll
            for (int m = 0; m < 4; ++m)
                #pragma unroll
                for (int n = 0; n < 2; ++n)
                    acc[m][n] = __builtin_amdgcn_mfma_f32_16x16x32_bf16(
                        af[m], bfr[n], acc[m][n], 0, 0, 0);
        }
        __syncthreads();
    }

    #pragma unroll
    for (int m = 0; m < 4; ++m) {
        int rbase = row0 + wr + m * 16 + (lane >> 4) * 4;
        #pragma unroll
        for (int n = 0; n < 2; ++n) {
            int col = col0 + wc + n * 16 + (lane & 15);
            #pragma unroll
            for (int r = 0; r < 4; ++r) {
                if (OBF) {
                    ((unsigned short*)Cv)[(size_t)(rbase + r) * ldc + col] =
                        f2bf(acc[m][n][r]);
                } else {
                    ((float*)Cv)[(size_t)(rbase + r) * ldc + col] = acc[m][n][r];
                }
            }
        }
    }
}

// ---------------------------------------------------------------------------
// MFMA split-K x_proj, 512-thread/8-wave variant (same high-occupancy
// transform as gemm_bb512). part[z] = ucbf[:, kb:kb+256] @ wXT^T (N=96 of
// 128, single col block). Grid (1, M/128, XKS).
// ---------------------------------------------------------------------------
__global__ __launch_bounds__(512) void xproj_splitk_bb512_kernel(
    const unsigned short* __restrict__ Abf, const unsigned short* __restrict__ BT,
    float* __restrict__ part)
{
    __shared__ unsigned short lds_a[128 * 64];
    __shared__ unsigned short lds_b[128 * 64];

    const int tid  = threadIdx.x;
    const int lane = tid & 63;
    const int w    = tid >> 6;
    const int wr   = (w >> 2) * 64;
    const int wc   = (w & 3) * 32;
    const int row0 = blockIdx.y * 128;
    const int kb   = blockIdx.z * XKCH;
    const int K    = DINNER;

    f32x4 acc[4][2];
    #pragma unroll
    for (int m = 0; m < 4; ++m)
        #pragma unroll
        for (int n = 0; n < 2; ++n)
            acc[m][n] = (f32x4){0.f, 0.f, 0.f, 0.f};

    for (int k0 = kb; k0 < kb + XKCH; k0 += 64) {
        #pragma unroll
        for (int j = 0; j < 2; ++j) {
            int c  = j * 512 + tid;
            int r  = c >> 3;
            int cc = c & 7;
            const char* asrc = (const char*)Abf +
                ((size_t)(row0 + r) * K + k0) * 2 + cc * 16;
            __builtin_amdgcn_global_load_lds(
                (const __attribute__((address_space(1))) void*)asrc,
                (__attribute__((address_space(3))) void*)((char*)lds_a + c * 16),
                16, 0, 0);
            const char* bsrc = (const char*)BT +
                ((size_t)r * K + k0) * 2 + cc * 16;
            __builtin_amdgcn_global_load_lds(
                (const __attribute__((address_space(1))) void*)bsrc,
                (__attribute__((address_space(3))) void*)((char*)lds_b + c * 16),
                16, 0, 0);
        }
        __syncthreads();

        #pragma unroll
        for (int kk = 0; kk < 2; ++kk) {
            bf16x8 af[4], bfr[2];
            #pragma unroll
            for (int m = 0; m < 4; ++m) {
                int r = wr + m * 16 + (lane & 15);
                int byteoff = r * 128 + ((kk * 64 + (lane >> 4) * 16) ^ ((r & 7) << 4));
                af[m] = *reinterpret_cast<const bf16x8*>((const char*)lds_a + byteoff);
            }
            #pragma unroll
            for (int n = 0; n < 2; ++n) {
                int r = wc + n * 16 + (lane & 15);
                int byteoff = r * 128 + ((kk * 64 + (lane >> 4) * 16) ^ ((r & 7) << 4));
                bfr[n] = *reinterpret_cast<const bf16x8*>((const char*)lds_b + byteoff);
            }
            #pragma unroll
            for (int m = 0; m < 4; ++m)
                #pragma unroll
                for (int n = 0; n < 2; ++n)
                    acc[m][n] = __builtin_amdgcn_mfma_f32_16x16x32_bf16(
                        af[m], bfr[n], acc[m][n], 0, 0, 0);
        }
        __syncthreads();
    }

    float* pbase = part + (size_t)blockIdx.z * MROWS * 96;
    #pragma unroll
    for (int m = 0; m < 4; ++m) {
        int rbase = row0 + wr + m * 16 + (lane >> 4) * 4;
        #pragma unroll
        for (int n = 0; n < 2; ++n) {
            int col = wc + n * 16 + (lane & 15);
            if (col < 96) {
                #pragma unroll
                for (int r = 0; r < 4; ++r)
                    pbase[(size_t)(rbase + r) * 96 + col] = acc[m][n][r];
            }
        }
    }
}

// Reduce XKS partials -> dbc fp32; cols<64 also emitted as pre-swizzled bf16.
__global__ __launch_bounds__(256) void xproj_reduce_kernel(
    const float* __restrict__ part, float* __restrict__ dbc,
    unsigned short* __restrict__ dtlo)
{
    int gid = blockIdx.x * 256 + threadIdx.x;
    float s = 0.f;
    #pragma unroll
    for (int k = 0; k < XKS; ++k)
        s += part[(size_t)k * MROWS * 96 + gid];
    dbc[gid] = s;
    int row = gid / 96;
    int col = gid - row * 96;
    if (col < 64)
        dtlo[(size_t)row * 64 + (col ^ ((row & 7) << 3))] = f2bf(s);
}

// ---------------------------------------------------------------------------
// dt_proj MFMA (K=64, one K-step): dtb = bf16(softplus(dtlo @ wDT^T + bias)).
// ---------------------------------------------------------------------------
__global__ __launch_bounds__(256) void gemm_dtproj_bb_kernel(
    const unsigned short* __restrict__ Abf, const unsigned short* __restrict__ BT,
    const float* __restrict__ bias, unsigned short* __restrict__ C)
{
    __shared__ unsigned short lds_a[128 * 64];
    __shared__ unsigned short lds_b[128 * 64];

    const int tid  = threadIdx.x;
    const int lane = tid & 63;
    const int w    = tid >> 6;
    const int wr   = (w >> 1) * 64;
    const int wc   = (w & 1) * 64;
    const int row0 = blockIdx.y * 128;
    const int col0 = blockIdx.x * 128;

    f32x4 acc[4][4];
    #pragma unroll
    for (int m = 0; m < 4; ++m)
        #pragma unroll
        for (int n = 0; n < 4; ++n)
            acc[m][n] = (f32x4){0.f, 0.f, 0.f, 0.f};

    #pragma unroll
    for (int j = 0; j < 4; ++j) {
        int c  = (j * 4 + w) * 64 + lane;
        int r  = c >> 3;
        int cc = c & 7;
        const char* asrc = (const char*)Abf + ((size_t)(row0 + r) * 64) * 2 + cc * 16;
        __builtin_amdgcn_global_load_lds(
            (const __attribute__((address_space(1))) void*)asrc,
            (__attribute__((address_space(3))) void*)((char*)lds_a + (j * 4 + w) * 1024),
            16, 0, 0);
        const char* bsrc = (const char*)BT + ((size_t)(col0 + r) * 64) * 2 + cc * 16;
        __builtin_amdgcn_global_load_lds(
            (const __attribute__((address_space(1))) void*)bsrc,
            (__attribute__((address_space(3))) void*)((char*)lds_b + (j * 4 + w) * 1024),
            16, 0, 0);
    }
    __syncthreads();

    #pragma unroll
    for (int kk = 0; kk < 2; ++kk) {
        bf16x8 af[4], bfr[4];
        #pragma unroll
        for (int m = 0; m < 4; ++m) {
            int r = wr + m * 16 + (lane & 15);
            int byteoff = r * 128 + ((kk * 64 + (lane >> 4) * 16) ^ ((r & 7) << 4));
            af[m] = *reinterpret_cast<const bf16x8*>((const char*)lds_a + byteoff);
        }
        #pragma unroll
        for (int n = 0; n < 4; ++n) {
            int r = wc + n * 16 + (lane & 15);
            int byteoff = r * 128 + ((kk * 64 + (lane >> 4) * 16) ^ ((r & 7) << 4));
            bfr[n] = *reinterpret_cast<const bf16x8*>((const char*)lds_b + byteoff);
        }
        #pragma unroll
        for (int m = 0; m < 4; ++m)
            #pragma unroll
            for (int n = 0; n < 4; ++n)
                acc[m][n] = __builtin_amdgcn_mfma_f32_16x16x32_bf16(
                    af[m], bfr[n], acc[m][n], 0, 0, 0);
    }

    #pragma unroll
    for (int m = 0; m < 4; ++m) {
        int rbase = row0 + wr + m * 16 + (lane >> 4) * 4;
        #pragma unroll
        for (int n = 0; n < 4; ++n) {
            int col = col0 + wc + n * 16 + (lane & 15);
            float bv = bias[col];
            #pragma unroll
            for (int r = 0; r < 4; ++r) {
                float v = acc[m][n][r] + bv;
                v = (v > 20.0f) ? v : log1pf(__expf(v));
                C[(size_t)(rbase + r) * DINNER + col] = f2bf(v);
            }
        }
    }
}

// ---------------------------------------------------------------------------
// Causal depthwise conv1d (width 4) + bias + silu, bf16 in -> swizzled bf16 out.
// ---------------------------------------------------------------------------
__global__ __launch_bounds__(256) void conv_silu_kernel(
    const unsigned short* __restrict__ xzb, const float* __restrict__ cw,
    const float* __restrict__ cb, unsigned short* __restrict__ ucbf)
{
    int gid = blockIdx.x * 256 + threadIdx.x;     // over MROWS * (DINNER/8)
    int row = gid >> 8;
    int d0  = (gid & 255) * 8;
    int t = row & (LSEQ - 1);

    uint4 uv[4];
    #pragma unroll
    for (int k = 0; k < 4; ++k) {
        if (t - 3 + k >= 0)
            uv[k] = *reinterpret_cast<const uint4*>(
                xzb + (size_t)(row + k - 3) * 4096 + d0);
        else
            uv[k] = (uint4){0u, 0u, 0u, 0u};
    }

    float v[8];
    #pragma unroll
    for (int i = 0; i < 8; ++i) {
        float acc = cb[d0 + i];
        float4 wv = *reinterpret_cast<const float4*>(cw + (size_t)(d0 + i) * 4);
        float wk[4] = {wv.x, wv.y, wv.z, wv.w};
        #pragma unroll
        for (int k = 0; k < 4; ++k) {
            unsigned int word = (&uv[k].x)[i >> 1];
            float u = __uint_as_float((i & 1) ? (word & 0xffff0000u) : (word << 16));
            acc = fmaf(u, wk[k], acc);
        }
        v[i] = acc * sigmoidf_(acc);
    }

    uint4 o;
    o.x = (unsigned)f2bf(v[0]) | ((unsigned)f2bf(v[1]) << 16);
    o.y = (unsigned)f2bf(v[2]) | ((unsigned)f2bf(v[3]) << 16);
    o.z = (unsigned)f2bf(v[4]) | ((unsigned)f2bf(v[5]) << 16);
    o.w = (unsigned)f2bf(v[6]) | ((unsigned)f2bf(v[7]) << 16);
    *reinterpret_cast<uint4*>(
        ucbf + (size_t)row * DINNER + (d0 ^ ((row & 7) << 3))) = o;
}

// ---------------------------------------------------------------------------
// Chunked scan, pass A — batched loads: 8-step groups, group g+1's 16
// independent loads issued before computing group g (T14 pattern).
// Note: for s = g*8+i, s&7 == i, so the ucbf XOR term is (i<<3).
// ---------------------------------------------------------------------------
__global__ __launch_bounds__(256) void scan_partial_kernel(
    const unsigned short* __restrict__ dtb, const unsigned short* __restrict__ ucbf,
    const float* __restrict__ dbc, const float* __restrict__ A_log,
    float* __restrict__ Pbuf, float* __restrict__ Ebuf)
{
    __shared__ float sB[CHUNK][NSTATE];
    const int tid = threadIdx.x;
    const int c = blockIdx.x;
    const int b = blockIdx.z;
    const int d = blockIdx.y * 256 + tid;
    const size_t row0 = (size_t)b * LSEQ + c * CHUNK;

    {
        int s = tid >> 2, f = tid & 3;
        float4 v = *reinterpret_cast<const float4*>(dbc + (row0 + s) * 96 + 64 + f * 4);
        *reinterpret_cast<float4*>(&sB[s][f * 4]) = v;
    }

    float An2[NSTATE];
    #pragma unroll
    for (int k = 0; k < 4; ++k) {
        float4 a = *reinterpret_cast<const float4*>(A_log + (size_t)d * NSTATE + k * 4);
        An2[k*4+0] = -__expf(a.x) * LOG2E;
        An2[k*4+1] = -__expf(a.y) * LOG2E;
        An2[k*4+2] = -__expf(a.z) * LOG2E;
        An2[k*4+3] = -__expf(a.w) * LOG2E;
    }
    const float c0 = An2[0];
    bool powok = true;
    #pragma unroll
    for (int n = 1; n < NSTATE; ++n)
        powok = powok && (fabsf(An2[n] - (n + 1) * c0) <= 1e-4f * (n + 1) * fabsf(c0));
    __syncthreads();

    float E[NSTATE];
    #pragma unroll
    for (int n = 0; n < NSTATE; ++n) E[n] = 0.f;
    float S = 0.f;

    float dtv[8], uv[8];
    #pragma unroll
    for (int i = 0; i < 8; ++i) {
        dtv[i] = bf2f(dtb[(row0 + i) * DINNER + d]);
        uv[i]  = bf2f(ucbf[(row0 + i) * DINNER + (d ^ (i << 3))]);
    }

    for (int g = 0; g < 8; ++g) {
        float dtn[8], un[8];
        if (g < 7) {
            #pragma unroll
            for (int i = 0; i < 8; ++i) {
                int s = (g + 1) * 8 + i;
                dtn[i] = bf2f(dtb[(row0 + s) * DINNER + d]);
                un[i]  = bf2f(ucbf[(row0 + s) * DINNER + (d ^ (i << 3))]);
            }
        }
        #pragma unroll
        for (int i = 0; i < 8; ++i) {
            int s = g * 8 + i;
            S += dtv[i];
            float du = dtv[i] * uv[i];
            float Bv[NSTATE];
            #pragma unroll
            for (int k = 0; k < 4; ++k)
                *reinterpret_cast<float4*>(&Bv[k*4]) =
                    *reinterpret_cast<const float4*>(&sB[s][k*4]);
            if (powok) {
                float q = EXP2F(dtv[i] * c0);
                float dA = q;
                #pragma unroll
                for (int n = 0; n < NSTATE; ++n) {
                    E[n] = fmaf(E[n], dA, du * Bv[n]);
                    dA *= q;
                }
            } else {
                #pragma unroll
                for (int n = 0; n < NSTATE; ++n) {
                    float qq = EXP2F(dtv[i] * An2[n]);
                    E[n] = fmaf(E[n], qq, du * Bv[n]);
                }
            }
        }
        #pragma unroll
        for (int i = 0; i < 8; ++i) { dtv[i] = dtn[i]; uv[i] = un[i]; }
    }

    size_t base = (((size_t)c * BSZ + b) * DINNER + d) * NSTATE;
    if (powok) {
        float R = EXP2F(c0 * S);
        float P = R;
        #pragma unroll
        for (int n = 0; n < NSTATE; ++n) {
            Pbuf[base + n] = P;
            Ebuf[base + n] = E[n];
            P *= R;
        }
    } else {
        #pragma unroll
        for (int n = 0; n < NSTATE; ++n) {
            Pbuf[base + n] = EXP2F(An2[n] * S);
            Ebuf[base + n] = E[n];
        }
    }
}

// ---------------------------------------------------------------------------
// Pass B — batched: preload 8 (P,E) pairs per group so 16 loads are in
// flight instead of 1 strided round-trip per chunk. Each (b,d,n) column is
// owned by one thread, so prefetching unwritten future rows is safe.
// ---------------------------------------------------------------------------
__global__ __launch_bounds__(256) void scan_prefix_kernel(
    float* __restrict__ Pbuf, const float* __restrict__ Ebuf)
{
    const int gid = blockIdx.x * 256 + threadIdx.x;
    const size_t stride = (size_t)BSZ * DINNER * NSTATE;
    size_t idx = gid;
    float h = 0.f;

    float Pv[8], Ev[8];
    #pragma unroll
    for (int i = 0; i < 8; ++i) {
        Pv[i] = Pbuf[idx + (size_t)i * stride];
        Ev[i] = Ebuf[idx + (size_t)i * stride];
    }
    for (int g = 0; g < 8; ++g) {
        float Pn[8], En[8];
        if (g < 7) {
            size_t nb = idx + (size_t)8 * stride;
            #pragma unroll
            for (int i = 0; i < 8; ++i) {
                Pn[i] = Pbuf[nb + (size_t)i * stride];
                En[i] = Ebuf[nb + (size_t)i * stride];
            }
        }
        #pragma unroll
        for (int i = 0; i < 8; ++i) {
            Pbuf[idx + (size_t)i * stride] = h;   // exclusive prefix (h0)
            h = fmaf(Pv[i], h, Ev[i]);
        }
        idx += (size_t)8 * stride;
        #pragma unroll
        for (int i = 0; i < 8; ++i) { Pv[i] = Pn[i]; Ev[i] = En[i]; }
    }
}

// ---------------------------------------------------------------------------
// Pass C — batched (4-step groups: dt,u,z = 12 loads in flight). For
// s = g*4+i, s&7 = (g&1)*4 + i -> XOR term ((((g&1)*4)+i)<<3).
// ---------------------------------------------------------------------------
__global__ __launch_bounds__(256) void scan_final_kernel(
    const unsigned short* __restrict__ dtb, const unsigned short* __restrict__ ucbf,
    const unsigned short* __restrict__ xzb, const float* __restrict__ dbc,
    const float* __restrict__ A_log, const float* __restrict__ Dp,
    const float* __restrict__ H0, unsigned short* __restrict__ ybf)
{
    __shared__ float sBC[CHUNK][2 * NSTATE];
    const int tid = threadIdx.x;
    const int c = blockIdx.x;
    const int b = blockIdx.z;
    const int d = blockIdx.y * 256 + tid;
    const size_t row0 = (size_t)b * LSEQ + c * CHUNK;

    {
        #pragma unroll
        for (int i = 0; i < 2; ++i) {
            int j = tid * 2 + i;
            int s = j >> 3, f = j & 7;
            float4 v = *reinterpret_cast<const float4*>(dbc + (row0 + s) * 96 + 64 + f * 4);
            *reinterpret_cast<float4*>(&sBC[s][f * 4]) = v;
        }
    }

    float An2[NSTATE];
    #pragma unroll
    for (int k = 0; k < 4; ++k) {
        float4 a = *reinterpret_cast<const float4*>(A_log + (size_t)d * NSTATE + k * 4);
        An2[k*4+0] = -__expf(a.x) * LOG2E;
        An2[k*4+1] = -__expf(a.y) * LOG2E;
        An2[k*4+2] = -__expf(a.z) * LOG2E;
        An2[k*4+3] = -__expf(a.w) * LOG2E;
    }
    const float c0 = An2[0];
    bool powok = true;
    #pragma unroll
    for (int n = 1; n < NSTATE; ++n)
        powok = powok && (fabsf(An2[n] - (n + 1) * c0) <= 1e-4f * (n + 1) * fabsf(c0));
    const float Dpd = Dp[d];

    float h[NSTATE];
    {
        size_t base = (((size_t)c * BSZ + b) * DINNER + d) * NSTATE;
        #pragma unroll
        for (int n = 0; n < NSTATE; ++n) h[n] = H0[base + n];
    }
    __syncthreads();

    float dtv[4], uv[4], zv[4];
    #pragma unroll
    for (int i = 0; i < 4; ++i) {
        dtv[i] = bf2f(dtb[(row0 + i) * DINNER + d]);
        uv[i]  = bf2f(ucbf[(row0 + i) * DINNER + (d ^ (i << 3))]);
        zv[i]  = bf2f(xzb[(row0 + i) * 4096 + 2048 + d]);
    }

    for (int g = 0; g < 16; ++g) {
        float dtn[4], un[4], zn[4];
        if (g < 15) {
            int xo = (((g + 1) & 1) << 2);
            #pragma unroll
            for (int i = 0; i < 4; ++i) {
                int s = (g + 1) * 4 + i;
                dtn[i] = bf2f(dtb[(row0 + s) * DINNER + d]);
                un[i]  = bf2f(ucbf[(row0 + s) * DINNER + (d ^ ((xo + i) << 3))]);
                zn[i]  = bf2f(xzb[(row0 + s) * 4096 + 2048 + d]);
            }
        }
        int xg = ((g & 1) << 2);
        #pragma unroll
        for (int i = 0; i < 4; ++i) {
            int s = g * 4 + i;
            float du = dtv[i] * uv[i];
            float Bv[NSTATE], Cv[NSTATE];
            #pragma unroll
            for (int k = 0; k < 4; ++k) {
                *reinterpret_cast<float4*>(&Bv[k*4]) =
                    *reinterpret_cast<const float4*>(&sBC[s][k*4]);
                *reinterpret_cast<float4*>(&Cv[k*4]) =
                    *reinterpret_cast<const float4*>(&sBC[s][16 + k*4]);
            }
            float y0 = 0.f, y1 = 0.f, y2 = 0.f, y3 = 0.f;
            if (powok) {
                float q = EXP2F(dtv[i] * c0);
                float dA = q;
                #pragma unroll
                for (int n = 0; n < NSTATE; ++n) {
                    h[n] = fmaf(h[n], dA, du * Bv[n]);
                    float& yk = (n & 3) == 0 ? y0 : (n & 3) == 1 ? y1 : (n & 3) == 2 ? y2 : y3;
                    yk = fmaf(h[n], Cv[n], yk);
                    dA *= q;
                }
            } else {
                #pragma unroll
                for (int n = 0; n < NSTATE; ++n) {
                    float qq = EXP2F(dtv[i] * An2[n]);
                    h[n] = fmaf(h[n], qq, du * Bv[n]);
                    float& yk = (n & 3) == 0 ? y0 : (n & 3) == 1 ? y1 : (n & 3) == 2 ? y2 : y3;
                    yk = fmaf(h[n], Cv[n], yk);
                }
            }
            float y = (y0 + y1) + (y2 + y3);
            float yg = (y + uv[i] * Dpd) * (zv[i] * sigmoidf_(zv[i]));
            ybf[(row0 + s) * DINNER + (d ^ ((xg + i) << 3))] = f2bf(yg);
        }
        #pragma unroll
        for (int i = 0; i < 4; ++i) { dtv[i] = dtn[i]; uv[i] = un[i]; zv[i] = zn[i]; }
    }
}

// ---------------------------------------------------------------------------
extern "C" void kernel_launch(void* const* d_in, const int* in_sizes, int n_in,
                              void* d_out, int out_size, void* d_ws, size_t ws_size,
                              hipStream_t stream)
{
    const float* x         = (const float*)d_in[0];
    const float* in_proj_w = (const float*)d_in[1];
    const float* conv_w    = (const float*)d_in[2];
    const float* conv_b    = (const float*)d_in[3];
    const float* x_proj_w  = (const float*)d_in[4];
    const float* dt_proj_w = (const float*)d_in[5];
    const float* dt_proj_b = (const float*)d_in[6];
    const float* A_log     = (const float*)d_in[7];
    const float* Dp        = (const float*)d_in[8];
    const float* out_proj_w= (const float*)d_in[9];
    float* out = (float*)d_out;

    // Workspace (208 MiB total) — same layout as rounds 9-14.
    char* base = (char*)d_ws;
    unsigned short* xzb  = (unsigned short*)base;
    unsigned short* dtb  = (unsigned short*)(base + (64ull << 20));
    unsigned short* ucbf = (unsigned short*)(base + (96ull << 20));
    float* dbc           = (float*)(base + (128ull << 20));
    unsigned short* wT_in  = (unsigned short*)(base + (131ull << 20));
    unsigned short* wT_out = (unsigned short*)(base + (139ull << 20));
    unsigned short* wXT    = (unsigned short*)(base + (143ull << 20));
    unsigned short* wDT    = (unsigned short*)(base + (143ull << 20) + (512ull << 10));
    char* U = base + (144ull << 20);
    unsigned short* xbf  = (unsigned short*)U;
    float* part          = (float*)U;
    unsigned short* dtlo = (unsigned short*)(U + (24ull << 20));
    float* Pbuf          = (float*)U;
    float* Ebuf          = (float*)(U + (16ull << 20));
    unsigned short* ybf  = (unsigned short*)(U + (32ull << 20));

    dim3 blk(256);
    dim3 blk512(512);

    // 0) fused operand prep (cvt x + all 4 weight transposes)
    prep_kernel<<<dim3(5728), blk, 0, stream>>>(
        x, xbf, in_proj_w, wT_in, out_proj_w, wT_out, x_proj_w, wXT, dt_proj_w, wDT);

    // 1) xzb = bf16(x @ in_proj_w)  — 512-thread high-occupancy variant
    gemm_bb512_kernel<1><<<dim3(32, 64), blk512, 0, stream>>>(
        xbf, wT_in, (void*)xzb, MROWS, 4096, 1024, 4096);

    // 2) ucbf = swz_bf16(silu(causal_conv(u) + conv_b))
    conv_silu_kernel<<<dim3((MROWS * (DINNER / 8)) / 256), blk, 0, stream>>>(
        xzb, conv_w, conv_b, ucbf);

    // 3) dbc = uc @ x_proj_w  (bf16 MFMA split-K 512-thr + reduce; emits dtlo)
    xproj_splitk_bb512_kernel<<<dim3(1, 64, XKS), blk512, 0, stream>>>(ucbf, wXT, part);
    xproj_reduce_kernel<<<dim3((MROWS * 96) / 256), blk, 0, stream>>>(part, dbc, dtlo);

    // 4) dtb = bf16(softplus(dtlo @ dt_proj_w + dt_proj_b))
    gemm_dtproj_bb_kernel<<<dim3(16, 64), blk, 0, stream>>>(dtlo, wDT, dt_proj_b, dtb);

    // 5) chunked selective scan (3 passes, batched loads) -> ybf
    scan_partial_kernel<<<dim3(NCHUNK, DINNER / 256, BSZ), blk, 0, stream>>>(
        dtb, ucbf, dbc, A_log, Pbuf, Ebuf);
    scan_prefix_kernel<<<dim3((BSZ * DINNER * NSTATE) / 256), blk, 0, stream>>>(Pbuf, Ebuf);
    scan_final_kernel<<<dim3(NCHUNK, DINNER / 256, BSZ), blk, 0, stream>>>(
        dtb, ucbf, xzb, dbc, A_log, Dp, Pbuf, ybf);

    // 6) out = y_gated @ out_proj_w (fp32 out) — 512-thread variant
    gemm_bb512_kernel<0><<<dim3(8, 64), blk512, 0, stream>>>(
        ybf, wT_out, (void*)out, MROWS, 1024, 2048, 1024);
}

// Round 16
// 373.417 us; speedup vs baseline: 1.0445x; 1.0445x over previous
//
#include <hip/hip_runtime.h>
#include <hip/hip_bf16.h>
#include <math.h>

#define BSZ 2
#define LSEQ 4096
#define DMODEL 1024
#define DINNER 2048
#define NSTATE 16
#define DTRANK 64
#define MROWS (BSZ * LSEQ)   // 8192
#define NCHUNK 64
#define CHUNK (LSEQ / NCHUNK)  // 64
#define XKS 8
#define XKCH (DINNER / XKS)    // 256

#if __has_builtin(__builtin_amdgcn_exp2f)
#define EXP2F(x) __builtin_amdgcn_exp2f(x)
#else
#define EXP2F(x) exp2f(x)
#endif
#define LOG2E 1.44269504088896f

typedef __attribute__((ext_vector_type(8))) short bf16x8;
typedef __attribute__((ext_vector_type(4))) float f32x4;

__device__ __forceinline__ float sigmoidf_(float x) { return 1.0f / (1.0f + __expf(-x)); }

__device__ __forceinline__ unsigned short f2bf(float x) {
    unsigned int u = __float_as_uint(x);
    u += 0x7fff + ((u >> 16) & 1);          // round-to-nearest-even
    return (unsigned short)(u >> 16);
}
__device__ __forceinline__ float bf2f(unsigned short b) {
    return __uint_as_float(((unsigned int)b) << 16);
}

// ---------------------------------------------------------------------------
// Fused operand prep (cvt x + 4 weight transposes), demuxed on blockIdx.
// Swizzle: element k of a 64-window stored at k ^ ((row&7)<<3).
// ---------------------------------------------------------------------------
__global__ __launch_bounds__(256) void prep_kernel(
    const float* __restrict__ x, unsigned short* __restrict__ xbf,
    const float* __restrict__ w_in, unsigned short* __restrict__ wT_in,
    const float* __restrict__ w_out, unsigned short* __restrict__ wT_out,
    const float* __restrict__ w_x, unsigned short* __restrict__ wXT,
    const float* __restrict__ w_dt, unsigned short* __restrict__ wDT)
{
    __shared__ float tile[64][65];
    const int id = blockIdx.x;
    const int t = threadIdx.x;

    if (id >= 1632) {   // cvt x -> xbf (K=1024, 128 groups of 8 per row)
        int gid = (id - 1632) * 256 + t;
        int m = gid >> 7;
        int g = gid & 127;
        size_t src = (size_t)m * 1024 + g * 8;
        float4 v0 = *reinterpret_cast<const float4*>(x + src);
        float4 v1 = *reinterpret_cast<const float4*>(x + src + 4);
        uint4 w;
        w.x = (unsigned)f2bf(v0.x) | ((unsigned)f2bf(v0.y) << 16);
        w.y = (unsigned)f2bf(v0.z) | ((unsigned)f2bf(v0.w) << 16);
        w.z = (unsigned)f2bf(v1.x) | ((unsigned)f2bf(v1.y) << 16);
        w.w = (unsigned)f2bf(v1.z) | ((unsigned)f2bf(v1.w) << 16);
        size_t dst = (size_t)m * 1024 + ((g * 8) ^ ((m & 7) << 3));
        *reinterpret_cast<uint4*>(xbf + dst) = w;
        return;
    }

    const float* W; unsigned short* WT; int K, Nsrc, nb, kb;
    if (id < 1024)      { W = w_in;  WT = wT_in;  K = 1024; Nsrc = 4096; nb = id & 63; kb = id >> 6; }
    else if (id < 1536) { int q = id - 1024; W = w_out; WT = wT_out; K = 2048; Nsrc = 1024; nb = q & 15; kb = q >> 4; }
    else if (id < 1600) { int q = id - 1536; W = w_x;   WT = wXT;   K = 2048; Nsrc = 96;   nb = q & 1;  kb = q >> 1; }
    else                { int q = id - 1600; W = w_dt;  WT = wDT;   K = 64;   Nsrc = 2048; nb = q;      kb = 0; }

    const int n0 = nb * 64;
    const int k0 = kb * 64;

    #pragma unroll
    for (int i = 0; i < 16; ++i) {
        int flat = i * 256 + t;
        int r = flat >> 6, c = flat & 63;
        tile[r][c] = (n0 + c < Nsrc) ? W[(size_t)(k0 + r) * Nsrc + n0 + c] : 0.0f;
    }
    __syncthreads();
    #pragma unroll
    for (int i = 0; i < 16; ++i) {
        int flat = i * 256 + t;
        int n = flat >> 6, k = flat & 63;
        int ks = k ^ ((n & 7) << 3);
        WT[(size_t)(n0 + n) * K + k0 + ks] = f2bf(tile[k][n]);
    }
}

// ---------------------------------------------------------------------------
// Pure-bf16 MFMA GEMM, 512 threads / 8 waves on a 128x128 tile; each wave
// owns 64x32 (acc = 4x2 f32x4 = 32 AGPR, half the register state of the
// 256-thread version -> ~52% occupancy, r14-proven: in_proj 74 us, 928 TF).
// Same verified 16x16x32 fragments, pre-swizzled operands, width-16
// global_load_lds (2 A + 2 B chunks/thread). OBF=1: bf16 C; OBF=0: fp32 C.
// ---------------------------------------------------------------------------
template<int OBF>
__global__ __launch_bounds__(512) void gemm_bb512_kernel(
    const unsigned short* __restrict__ Abf, const unsigned short* __restrict__ BT,
    void* __restrict__ Cv, int M, int N, int K, int ldc)
{
    __shared__ unsigned short lds_a[128 * 64];
    __shared__ unsigned short lds_b[128 * 64];

    const int tid  = threadIdx.x;
    const int lane = tid & 63;
    const int w    = tid >> 6;            // 0..7
    const int wr   = (w >> 2) * 64;       // 0 or 64
    const int wc   = (w & 3) * 32;        // 0,32,64,96
    const int row0 = blockIdx.y * 128;
    const int col0 = blockIdx.x * 128;

    f32x4 acc[4][2];
    #pragma unroll
    for (int m = 0; m < 4; ++m)
        #pragma unroll
        for (int n = 0; n < 2; ++n)
            acc[m][n] = (f32x4){0.f, 0.f, 0.f, 0.f};

    for (int k0 = 0; k0 < K; k0 += 64) {
        #pragma unroll
        for (int j = 0; j < 2; ++j) {
            int c  = j * 512 + tid;       // 16B chunk id, 0..1023
            int r  = c >> 3;
            int cc = c & 7;
            const char* asrc = (const char*)Abf +
                ((size_t)(row0 + r) * K + k0) * 2 + cc * 16;
            __builtin_amdgcn_global_load_lds(
                (const __attribute__((address_space(1))) void*)asrc,
                (__attribute__((address_space(3))) void*)((char*)lds_a + c * 16),
                16, 0, 0);
            const char* bsrc = (const char*)BT +
                ((size_t)(col0 + r) * K + k0) * 2 + cc * 16;
            __builtin_amdgcn_global_load_lds(
                (const __attribute__((address_space(1))) void*)bsrc,
                (__attribute__((address_space(3))) void*)((char*)lds_b + c * 16),
                16, 0, 0);
        }
        __syncthreads();

        #pragma unroll
        for (int kk = 0; kk < 2; ++kk) {
            bf16x8 af[4], bfr[2];
            #pragma unroll
            for (int m = 0; m < 4; ++m) {
                int r = wr + m * 16 + (lane & 15);
                int byteoff = r * 128 + ((kk * 64 + (lane >> 4) * 16) ^ ((r & 7) << 4));
                af[m] = *reinterpret_cast<const bf16x8*>((const char*)lds_a + byteoff);
            }
            #pragma unroll
            for (int n = 0; n < 2; ++n) {
                int r = wc + n * 16 + (lane & 15);
                int byteoff = r * 128 + ((kk * 64 + (lane >> 4) * 16) ^ ((r & 7) << 4));
                bfr[n] = *reinterpret_cast<const bf16x8*>((const char*)lds_b + byteoff);
            }
            #pragma unroll
            for (int m = 0; m < 4; ++m)
                #pragma unroll
                for (int n = 0; n < 2; ++n)
                    acc[m][n] = __builtin_amdgcn_mfma_f32_16x16x32_bf16(
                        af[m], bfr[n], acc[m][n], 0, 0, 0);
        }
        __syncthreads();
    }

    #pragma unroll
    for (int m = 0; m < 4; ++m) {
        int rbase = row0 + wr + m * 16 + (lane >> 4) * 4;
        #pragma unroll
        for (int n = 0; n < 2; ++n) {
            int col = col0 + wc + n * 16 + (lane & 15);
            #pragma unroll
            for (int r = 0; r < 4; ++r) {
                if (OBF) {
                    ((unsigned short*)Cv)[(size_t)(rbase + r) * ldc + col] =
                        f2bf(acc[m][n][r]);
                } else {
                    ((float*)Cv)[(size_t)(rbase + r) * ldc + col] = acc[m][n][r];
                }
            }
        }
    }
}

// ---------------------------------------------------------------------------
// MFMA split-K x_proj (16x16 fragments, 256 thr): part[z] = ucbf @ wXT^T.
// ---------------------------------------------------------------------------
__global__ __launch_bounds__(256) void xproj_splitk_bb_kernel(
    const unsigned short* __restrict__ Abf, const unsigned short* __restrict__ BT,
    float* __restrict__ part)
{
    __shared__ unsigned short lds_a[128 * 64];
    __shared__ unsigned short lds_b[128 * 64];

    const int tid  = threadIdx.x;
    const int lane = tid & 63;
    const int w    = tid >> 6;
    const int wr   = (w >> 1) * 64;
    const int wc   = (w & 1) * 64;
    const int row0 = blockIdx.y * 128;
    const int kb   = blockIdx.z * XKCH;
    const int K    = DINNER;

    f32x4 acc[4][4];
    #pragma unroll
    for (int m = 0; m < 4; ++m)
        #pragma unroll
        for (int n = 0; n < 4; ++n)
            acc[m][n] = (f32x4){0.f, 0.f, 0.f, 0.f};

    for (int k0 = kb; k0 < kb + XKCH; k0 += 64) {
        #pragma unroll
        for (int j = 0; j < 4; ++j) {
            int c  = (j * 4 + w) * 64 + lane;
            int r  = c >> 3;
            int cc = c & 7;
            const char* asrc = (const char*)Abf +
                ((size_t)(row0 + r) * K + k0) * 2 + cc * 16;
            __builtin_amdgcn_global_load_lds(
                (const __attribute__((address_space(1))) void*)asrc,
                (__attribute__((address_space(3))) void*)((char*)lds_a + (j * 4 + w) * 1024),
                16, 0, 0);
            const char* bsrc = (const char*)BT +
                ((size_t)r * K + k0) * 2 + cc * 16;
            __builtin_amdgcn_global_load_lds(
                (const __attribute__((address_space(1))) void*)bsrc,
                (__attribute__((address_space(3))) void*)((char*)lds_b + (j * 4 + w) * 1024),
                16, 0, 0);
        }
        __syncthreads();

        #pragma unroll
        for (int kk = 0; kk < 2; ++kk) {
            bf16x8 af[4], bfr[4];
            #pragma unroll
            for (int m = 0; m < 4; ++m) {
                int r = wr + m * 16 + (lane & 15);
                int byteoff = r * 128 + ((kk * 64 + (lane >> 4) * 16) ^ ((r & 7) << 4));
                af[m] = *reinterpret_cast<const bf16x8*>((const char*)lds_a + byteoff);
            }
            #pragma unroll
            for (int n = 0; n < 4; ++n) {
                int r = wc + n * 16 + (lane & 15);
                int byteoff = r * 128 + ((kk * 64 + (lane >> 4) * 16) ^ ((r & 7) << 4));
                bfr[n] = *reinterpret_cast<const bf16x8*>((const char*)lds_b + byteoff);
            }
            #pragma unroll
            for (int m = 0; m < 4; ++m)
                #pragma unroll
                for (int n = 0; n < 4; ++n)
                    acc[m][n] = __builtin_amdgcn_mfma_f32_16x16x32_bf16(
                        af[m], bfr[n], acc[m][n], 0, 0, 0);
        }
        __syncthreads();
    }

    float* pbase = part + (size_t)blockIdx.z * MROWS * 96;
    #pragma unroll
    for (int m = 0; m < 4; ++m) {
        int rbase = row0 + wr + m * 16 + (lane >> 4) * 4;
        #pragma unroll
        for (int n = 0; n < 4; ++n) {
            int col = wc + n * 16 + (lane & 15);
            if (col < 96) {
                #pragma unroll
                for (int r = 0; r < 4; ++r)
                    pbase[(size_t)(rbase + r) * 96 + col] = acc[m][n][r];
            }
        }
    }
}

// Reduce XKS partials -> dbc fp32; cols<64 also emitted as pre-swizzled bf16.
__global__ __launch_bounds__(256) void xproj_reduce_kernel(
    const float* __restrict__ part, float* __restrict__ dbc,
    unsigned short* __restrict__ dtlo)
{
    int gid = blockIdx.x * 256 + threadIdx.x;
    float s = 0.f;
    #pragma unroll
    for (int k = 0; k < XKS; ++k)
        s += part[(size_t)k * MROWS * 96 + gid];
    dbc[gid] = s;
    int row = gid / 96;
    int col = gid - row * 96;
    if (col < 64)
        dtlo[(size_t)row * 64 + (col ^ ((row & 7) << 3))] = f2bf(s);
}

// ---------------------------------------------------------------------------
// dt_proj MFMA (K=64, one K-step): dtb = bf16(softplus(dtlo @ wDT^T + bias)).
// ---------------------------------------------------------------------------
__global__ __launch_bounds__(256) void gemm_dtproj_bb_kernel(
    const unsigned short* __restrict__ Abf, const unsigned short* __restrict__ BT,
    const float* __restrict__ bias, unsigned short* __restrict__ C)
{
    __shared__ unsigned short lds_a[128 * 64];
    __shared__ unsigned short lds_b[128 * 64];

    const int tid  = threadIdx.x;
    const int lane = tid & 63;
    const int w    = tid >> 6;
    const int wr   = (w >> 1) * 64;
    const int wc   = (w & 1) * 64;
    const int row0 = blockIdx.y * 128;
    const int col0 = blockIdx.x * 128;

    f32x4 acc[4][4];
    #pragma unroll
    for (int m = 0; m < 4; ++m)
        #pragma unroll
        for (int n = 0; n < 4; ++n)
            acc[m][n] = (f32x4){0.f, 0.f, 0.f, 0.f};

    #pragma unroll
    for (int j = 0; j < 4; ++j) {
        int c  = (j * 4 + w) * 64 + lane;
        int r  = c >> 3;
        int cc = c & 7;
        const char* asrc = (const char*)Abf + ((size_t)(row0 + r) * 64) * 2 + cc * 16;
        __builtin_amdgcn_global_load_lds(
            (const __attribute__((address_space(1))) void*)asrc,
            (__attribute__((address_space(3))) void*)((char*)lds_a + (j * 4 + w) * 1024),
            16, 0, 0);
        const char* bsrc = (const char*)BT + ((size_t)(col0 + r) * 64) * 2 + cc * 16;
        __builtin_amdgcn_global_load_lds(
            (const __attribute__((address_space(1))) void*)bsrc,
            (__attribute__((address_space(3))) void*)((char*)lds_b + (j * 4 + w) * 1024),
            16, 0, 0);
    }
    __syncthreads();

    #pragma unroll
    for (int kk = 0; kk < 2; ++kk) {
        bf16x8 af[4], bfr[4];
        #pragma unroll
        for (int m = 0; m < 4; ++m) {
            int r = wr + m * 16 + (lane & 15);
            int byteoff = r * 128 + ((kk * 64 + (lane >> 4) * 16) ^ ((r & 7) << 4));
            af[m] = *reinterpret_cast<const bf16x8*>((const char*)lds_a + byteoff);
        }
        #pragma unroll
        for (int n = 0; n < 4; ++n) {
            int r = wc + n * 16 + (lane & 15);
            int byteoff = r * 128 + ((kk * 64 + (lane >> 4) * 16) ^ ((r & 7) << 4));
            bfr[n] = *reinterpret_cast<const bf16x8*>((const char*)lds_b + byteoff);
        }
        #pragma unroll
        for (int m = 0; m < 4; ++m)
            #pragma unroll
            for (int n = 0; n < 4; ++n)
                acc[m][n] = __builtin_amdgcn_mfma_f32_16x16x32_bf16(
                    af[m], bfr[n], acc[m][n], 0, 0, 0);
    }

    #pragma unroll
    for (int m = 0; m < 4; ++m) {
        int rbase = row0 + wr + m * 16 + (lane >> 4) * 4;
        #pragma unroll
        for (int n = 0; n < 4; ++n) {
            int col = col0 + wc + n * 16 + (lane & 15);
            float bv = bias[col];
            #pragma unroll
            for (int r = 0; r < 4; ++r) {
                float v = acc[m][n][r] + bv;
                v = (v > 20.0f) ? v : log1pf(__expf(v));
                C[(size_t)(rbase + r) * DINNER + col] = f2bf(v);
            }
        }
    }
}

// ---------------------------------------------------------------------------
// Causal depthwise conv1d (width 4) + bias + silu, bf16 in -> swizzled bf16 out.
// ---------------------------------------------------------------------------
__global__ __launch_bounds__(256) void conv_silu_kernel(
    const unsigned short* __restrict__ xzb, const float* __restrict__ cw,
    const float* __restrict__ cb, unsigned short* __restrict__ ucbf)
{
    int gid = blockIdx.x * 256 + threadIdx.x;     // over MROWS * (DINNER/8)
    int row = gid >> 8;
    int d0  = (gid & 255) * 8;
    int t = row & (LSEQ - 1);

    uint4 uv[4];
    #pragma unroll
    for (int k = 0; k < 4; ++k) {
        if (t - 3 + k >= 0)
            uv[k] = *reinterpret_cast<const uint4*>(
                xzb + (size_t)(row + k - 3) * 4096 + d0);
        else
            uv[k] = (uint4){0u, 0u, 0u, 0u};
    }

    float v[8];
    #pragma unroll
    for (int i = 0; i < 8; ++i) {
        float acc = cb[d0 + i];
        float4 wv = *reinterpret_cast<const float4*>(cw + (size_t)(d0 + i) * 4);
        float wk[4] = {wv.x, wv.y, wv.z, wv.w};
        #pragma unroll
        for (int k = 0; k < 4; ++k) {
            unsigned int word = (&uv[k].x)[i >> 1];
            float u = __uint_as_float((i & 1) ? (word & 0xffff0000u) : (word << 16));
            acc = fmaf(u, wk[k], acc);
        }
        v[i] = acc * sigmoidf_(acc);
    }

    uint4 o;
    o.x = (unsigned)f2bf(v[0]) | ((unsigned)f2bf(v[1]) << 16);
    o.y = (unsigned)f2bf(v[2]) | ((unsigned)f2bf(v[3]) << 16);
    o.z = (unsigned)f2bf(v[4]) | ((unsigned)f2bf(v[5]) << 16);
    o.w = (unsigned)f2bf(v[6]) | ((unsigned)f2bf(v[7]) << 16);
    *reinterpret_cast<uint4*>(
        ucbf + (size_t)row * DINNER + (d0 ^ ((row & 7) << 3))) = o;
}

// ---------------------------------------------------------------------------
// Chunked scan, pass A, with geometric-A fast path (checked at runtime).
// Simple 1-step prefetch (r14 form — batched variant regressed, VALU-bound).
// ---------------------------------------------------------------------------
__global__ __launch_bounds__(256) void scan_partial_kernel(
    const unsigned short* __restrict__ dtb, const unsigned short* __restrict__ ucbf,
    const float* __restrict__ dbc, const float* __restrict__ A_log,
    float* __restrict__ Pbuf, float* __restrict__ Ebuf)
{
    __shared__ float sB[CHUNK][NSTATE];
    const int tid = threadIdx.x;
    const int c = blockIdx.x;
    const int b = blockIdx.z;
    const int d = blockIdx.y * 256 + tid;
    const size_t row0 = (size_t)b * LSEQ + c * CHUNK;

    {
        int s = tid >> 2, f = tid & 3;
        float4 v = *reinterpret_cast<const float4*>(dbc + (row0 + s) * 96 + 64 + f * 4);
        *reinterpret_cast<float4*>(&sB[s][f * 4]) = v;
    }

    float An2[NSTATE];
    #pragma unroll
    for (int k = 0; k < 4; ++k) {
        float4 a = *reinterpret_cast<const float4*>(A_log + (size_t)d * NSTATE + k * 4);
        An2[k*4+0] = -__expf(a.x) * LOG2E;
        An2[k*4+1] = -__expf(a.y) * LOG2E;
        An2[k*4+2] = -__expf(a.z) * LOG2E;
        An2[k*4+3] = -__expf(a.w) * LOG2E;
    }
    const float c0 = An2[0];
    bool powok = true;
    #pragma unroll
    for (int n = 1; n < NSTATE; ++n)
        powok = powok && (fabsf(An2[n] - (n + 1) * c0) <= 1e-4f * (n + 1) * fabsf(c0));
    __syncthreads();

    float E[NSTATE];
    #pragma unroll
    for (int n = 0; n < NSTATE; ++n) E[n] = 0.f;
    float S = 0.f;

    float dtc = bf2f(dtb[row0 * DINNER + d]);
    float ucv = bf2f(ucbf[row0 * DINNER + d]);
    for (int s = 0; s < CHUNK; ++s) {
        float dtn = 0.f, un = 0.f;
        if (s + 1 < CHUNK) {
            dtn = bf2f(dtb[(row0 + s + 1) * DINNER + d]);
            un  = bf2f(ucbf[(row0 + s + 1) * DINNER + (d ^ (((s + 1) & 7) << 3))]);
        }
        S += dtc;
        float du = dtc * ucv;
        float Bv[NSTATE];
        #pragma unroll
        for (int k = 0; k < 4; ++k)
            *reinterpret_cast<float4*>(&Bv[k*4]) =
                *reinterpret_cast<const float4*>(&sB[s][k*4]);
        if (powok) {
            float q = EXP2F(dtc * c0);
            float dA = q;
            #pragma unroll
            for (int n = 0; n < NSTATE; ++n) {
                E[n] = fmaf(E[n], dA, du * Bv[n]);
                dA *= q;
            }
        } else {
            #pragma unroll
            for (int n = 0; n < NSTATE; ++n) {
                float qq = EXP2F(dtc * An2[n]);
                E[n] = fmaf(E[n], qq, du * Bv[n]);
            }
        }
        dtc = dtn; ucv = un;
    }

    size_t base = (((size_t)c * BSZ + b) * DINNER + d) * NSTATE;
    if (powok) {
        float R = EXP2F(c0 * S);
        float P = R;
        #pragma unroll
        for (int n = 0; n < NSTATE; ++n) {
            Pbuf[base + n] = P;
            Ebuf[base + n] = E[n];
            P *= R;
        }
    } else {
        #pragma unroll
        for (int n = 0; n < NSTATE; ++n) {
            Pbuf[base + n] = EXP2F(An2[n] * S);
            Ebuf[base + n] = E[n];
        }
    }
}

// ---------------------------------------------------------------------------
// Pass B: exclusive scan over chunks per (b,d,n); h0 written IN PLACE over P.
// ---------------------------------------------------------------------------
__global__ __launch_bounds__(256) void scan_prefix_kernel(
    float* __restrict__ Pbuf, const float* __restrict__ Ebuf)
{
    const int gid = blockIdx.x * 256 + threadIdx.x;
    const size_t stride = (size_t)BSZ * DINNER * NSTATE;
    size_t idx = gid;
    float h = 0.f;
    for (int c = 0; c < NCHUNK; ++c) {
        float P = Pbuf[idx];
        float Ev = Ebuf[idx];
        Pbuf[idx] = h;
        h = fmaf(P, h, Ev);
        idx += stride;
    }
}

// ---------------------------------------------------------------------------
// Pass C: local scan seeded with h0; fuse y, skip, gate; emit swizzled bf16
// ybf. Geometric fast path; simple 1-step prefetch (r14 form).
// ---------------------------------------------------------------------------
__global__ __launch_bounds__(256) void scan_final_kernel(
    const unsigned short* __restrict__ dtb, const unsigned short* __restrict__ ucbf,
    const unsigned short* __restrict__ xzb, const float* __restrict__ dbc,
    const float* __restrict__ A_log, const float* __restrict__ Dp,
    const float* __restrict__ H0, unsigned short* __restrict__ ybf)
{
    __shared__ float sBC[CHUNK][2 * NSTATE];
    const int tid = threadIdx.x;
    const int c = blockIdx.x;
    const int b = blockIdx.z;
    const int d = blockIdx.y * 256 + tid;
    const size_t row0 = (size_t)b * LSEQ + c * CHUNK;

    {
        #pragma unroll
        for (int i = 0; i < 2; ++i) {
            int j = tid * 2 + i;
            int s = j >> 3, f = j & 7;
            float4 v = *reinterpret_cast<const float4*>(dbc + (row0 + s) * 96 + 64 + f * 4);
            *reinterpret_cast<float4*>(&sBC[s][f * 4]) = v;
        }
    }

    float An2[NSTATE];
    #pragma unroll
    for (int k = 0; k < 4; ++k) {
        float4 a = *reinterpret_cast<const float4*>(A_log + (size_t)d * NSTATE + k * 4);
        An2[k*4+0] = -__expf(a.x) * LOG2E;
        An2[k*4+1] = -__expf(a.y) * LOG2E;
        An2[k*4+2] = -__expf(a.z) * LOG2E;
        An2[k*4+3] = -__expf(a.w) * LOG2E;
    }
    const float c0 = An2[0];
    bool powok = true;
    #pragma unroll
    for (int n = 1; n < NSTATE; ++n)
        powok = powok && (fabsf(An2[n] - (n + 1) * c0) <= 1e-4f * (n + 1) * fabsf(c0));
    const float Dpd = Dp[d];

    float h[NSTATE];
    {
        size_t base = (((size_t)c * BSZ + b) * DINNER + d) * NSTATE;
        #pragma unroll
        for (int n = 0; n < NSTATE; ++n) h[n] = H0[base + n];
    }
    __syncthreads();

    float dtc = bf2f(dtb[row0 * DINNER + d]);
    float ucv = bf2f(ucbf[row0 * DINNER + d]);
    float zc  = bf2f(xzb[row0 * 4096 + 2048 + d]);
    for (int s = 0; s < CHUNK; ++s) {
        float dtn = 0.f, un = 0.f, zn = 0.f;
        if (s + 1 < CHUNK) {
            dtn = bf2f(dtb[(row0 + s + 1) * DINNER + d]);
            un  = bf2f(ucbf[(row0 + s + 1) * DINNER + (d ^ (((s + 1) & 7) << 3))]);
            zn  = bf2f(xzb[(row0 + s + 1) * 4096 + 2048 + d]);
        }
        float du = dtc * ucv;
        float Bv[NSTATE], Cv[NSTATE];
        #pragma unroll
        for (int k = 0; k < 4; ++k) {
            *reinterpret_cast<float4*>(&Bv[k*4]) =
                *reinterpret_cast<const float4*>(&sBC[s][k*4]);
            *reinterpret_cast<float4*>(&Cv[k*4]) =
                *reinterpret_cast<const float4*>(&sBC[s][16 + k*4]);
        }
        float y0 = 0.f, y1 = 0.f, y2 = 0.f, y3 = 0.f;
        if (powok) {
            float q = EXP2F(dtc * c0);
            float dA = q;
            #pragma unroll
            for (int n = 0; n < NSTATE; ++n) {
                h[n] = fmaf(h[n], dA, du * Bv[n]);
                float& yk = (n & 3) == 0 ? y0 : (n & 3) == 1 ? y1 : (n & 3) == 2 ? y2 : y3;
                yk = fmaf(h[n], Cv[n], yk);
                dA *= q;
            }
        } else {
            #pragma unroll
            for (int n = 0; n < NSTATE; ++n) {
                float qq = EXP2F(dtc * An2[n]);
                h[n] = fmaf(h[n], qq, du * Bv[n]);
                float& yk = (n & 3) == 0 ? y0 : (n & 3) == 1 ? y1 : (n & 3) == 2 ? y2 : y3;
                yk = fmaf(h[n], Cv[n], yk);
            }
        }
        float y = (y0 + y1) + (y2 + y3);
        float yg = (y + ucv * Dpd) * (zc * sigmoidf_(zc));
        ybf[(row0 + s) * DINNER + (d ^ ((s & 7) << 3))] = f2bf(yg);
        dtc = dtn; ucv = un; zc = zn;
    }
}

// ---------------------------------------------------------------------------
extern "C" void kernel_launch(void* const* d_in, const int* in_sizes, int n_in,
                              void* d_out, int out_size, void* d_ws, size_t ws_size,
                              hipStream_t stream)
{
    const float* x         = (const float*)d_in[0];
    const float* in_proj_w = (const float*)d_in[1];
    const float* conv_w    = (const float*)d_in[2];
    const float* conv_b    = (const float*)d_in[3];
    const float* x_proj_w  = (const float*)d_in[4];
    const float* dt_proj_w = (const float*)d_in[5];
    const float* dt_proj_b = (const float*)d_in[6];
    const float* A_log     = (const float*)d_in[7];
    const float* Dp        = (const float*)d_in[8];
    const float* out_proj_w= (const float*)d_in[9];
    float* out = (float*)d_out;

    // Workspace (208 MiB total) — same layout as rounds 9-14.
    char* base = (char*)d_ws;
    unsigned short* xzb  = (unsigned short*)base;
    unsigned short* dtb  = (unsigned short*)(base + (64ull << 20));
    unsigned short* ucbf = (unsigned short*)(base + (96ull << 20));
    float* dbc           = (float*)(base + (128ull << 20));
    unsigned short* wT_in  = (unsigned short*)(base + (131ull << 20));
    unsigned short* wT_out = (unsigned short*)(base + (139ull << 20));
    unsigned short* wXT    = (unsigned short*)(base + (143ull << 20));
    unsigned short* wDT    = (unsigned short*)(base + (143ull << 20) + (512ull << 10));
    char* U = base + (144ull << 20);
    unsigned short* xbf  = (unsigned short*)U;
    float* part          = (float*)U;
    unsigned short* dtlo = (unsigned short*)(U + (24ull << 20));
    float* Pbuf          = (float*)U;
    float* Ebuf          = (float*)(U + (16ull << 20));
    unsigned short* ybf  = (unsigned short*)(U + (32ull << 20));

    dim3 blk(256);
    dim3 blk512(512);

    // 0) fused operand prep (cvt x + all 4 weight transposes)
    prep_kernel<<<dim3(5728), blk, 0, stream>>>(
        x, xbf, in_proj_w, wT_in, out_proj_w, wT_out, x_proj_w, wXT, dt_proj_w, wDT);

    // 1) xzb = bf16(x @ in_proj_w)  — 512-thread high-occupancy variant
    gemm_bb512_kernel<1><<<dim3(32, 64), blk512, 0, stream>>>(
        xbf, wT_in, (void*)xzb, MROWS, 4096, 1024, 4096);

    // 2) ucbf = swz_bf16(silu(causal_conv(u) + conv_b))
    conv_silu_kernel<<<dim3((MROWS * (DINNER / 8)) / 256), blk, 0, stream>>>(
        xzb, conv_w, conv_b, ucbf);

    // 3) dbc = uc @ x_proj_w  (bf16 MFMA split-K + reduce; emits dtlo bf16)
    xproj_splitk_bb_kernel<<<dim3(1, 64, XKS), blk, 0, stream>>>(ucbf, wXT, part);
    xproj_reduce_kernel<<<dim3((MROWS * 96) / 256), blk, 0, stream>>>(part, dbc, dtlo);

    // 4) dtb = bf16(softplus(dtlo @ dt_proj_w + dt_proj_b))
    gemm_dtproj_bb_kernel<<<dim3(16, 64), blk, 0, stream>>>(dtlo, wDT, dt_proj_b, dtb);

    // 5) chunked selective scan (3 passes) -> ybf (swizzled bf16)
    scan_partial_kernel<<<dim3(NCHUNK, DINNER / 256, BSZ), blk, 0, stream>>>(
        dtb, ucbf, dbc, A_log, Pbuf, Ebuf);
    scan_prefix_kernel<<<dim3((BSZ * DINNER * NSTATE) / 256), blk, 0, stream>>>(Pbuf, Ebuf);
    scan_final_kernel<<<dim3(NCHUNK, DINNER / 256, BSZ), blk, 0, stream>>>(
        dtb, ucbf, xzb, dbc, A_log, Dp, Pbuf, ybf);

    // 6) out = y_gated @ out_proj_w (fp32 out) — 512-thread variant
    gemm_bb512_kernel<0><<<dim3(8, 64), blk512, 0, stream>>>(
        ybf, wT_out, (void*)out, MROWS, 1024, 2048, 1024);
}